// Round 2
// baseline (191.118 us; speedup 1.0000x reference)
//
#include <hip/hip_runtime.h>

// Edge (replicate) pad, width 2 on H and W.
// In:  (32, 256, 56, 56) fp32  -> NC = 8192 planes of 56x56
// Out: (32, 256, 60, 60) fp32
//
// v3 = v2 with launch-size fix (out_size is in ELEMENTS, not bytes).
//
// All memory ops are naturally-aligned dwordx4.
// 16 lanes per output row (15 store, lane 15 pad). Lane l loads the ALIGNED
// input float4 at 4*min(l,13); the -2 shifted window [4l-2, 4l+2) is built as
// (prev.z, prev.w, own.x, own.y) where "prev" comes from DPP row_shr:1 —
// a 16-lane row shift that exactly matches the 16-lane-per-image-row mapping,
// so the shuffle never crosses an image row. Edge lanes are cndmask fixups:
//   l=0 : v = (x, x, x, y)            (own load at base 0)
//   l=14: v = (a, b, b, b)            (a,b = lane13's z,w = s54,s55)
//   else: v = (a, b, x, y)
// 1 aligned load + 1 aligned NT store per active lane; no divergent memory.

#define IN_H  56
#define IN_W  56
#define OUT_H 60
#define OUT_W 60
#define PAD   2
#define W4    (OUT_W / 4)   // 15 float4 per output row
#define LPR   16            // lanes per row: 15 active + 1 pad (= DPP row size)

typedef float f4a __attribute__((ext_vector_type(4), aligned(16)));

__device__ __forceinline__ float dpp_row_shr1(float x) {
    // lane l (within its 16-lane DPP row) receives lane l-1's x.
    // lane 0 of each row keeps old (=own) — always overridden by cndmask.
    int xi = __builtin_bit_cast(int, x);
    int r  = __builtin_amdgcn_update_dpp(xi, xi, 0x111 /*row_shr:1*/,
                                         0xf /*row_mask*/, 0xf /*bank_mask*/,
                                         false /*bound_ctrl: keep old*/);
    return __builtin_bit_cast(float, r);
}

__global__ __launch_bounds__(256) void pad2d_edge_kernel(
    const float* __restrict__ in, float* __restrict__ out, int n_thr) {
    int idx = blockIdx.x * blockDim.x + threadIdx.x;
    if (idx >= n_thr) return;           // n_thr is a multiple of 256: whole
                                        // 16-lane DPP rows drop together.
    int l = idx & (LPR - 1);            // lane within output row
    int t = idx >> 4;                   // nc*OUT_H + oh
    int oh = t % OUT_H;                 // single magic-div pair remains
    int nc = t / OUT_H;

    int ih = min(max(oh - PAD, 0), IN_H - 1);
    const f4a* src = reinterpret_cast<const f4a*>(
        in + (size_t)nc * (IN_H * IN_W) + (size_t)ih * IN_W);

    // Aligned 16B load; lanes 14/15 clamp to the last input vec (13).
    f4a u = src[min(l, IN_W / 4 - 1)];

    float a = dpp_row_shr1(u.z);        // s[4l-2] for l>=1
    float b = dpp_row_shr1(u.w);        // s[4l-1] for l>=1

    f4a v;
    v.x = (l == 0)      ? u.x : a;
    v.y = (l == 0)      ? u.x : b;
    v.z = (l == W4 - 1) ? b   : u.x;
    v.w = (l == W4 - 1) ? b   : u.y;

    if (l < W4)
        __builtin_nontemporal_store(
            v, reinterpret_cast<f4a*>(out) + (size_t)t * W4 + l);
}

extern "C" void kernel_launch(void* const* d_in, const int* in_sizes, int n_in,
                              void* d_out, int out_size, void* d_ws, size_t ws_size,
                              hipStream_t stream) {
    const float* x = (const float*)d_in[0];
    float* out = (float*)d_out;

    // out_size is in ELEMENTS (floats): 32*256*60*60 = 29,491,200.
    int nc_planes = out_size / (OUT_H * OUT_W);    // 8192
    int n_thr = nc_planes * OUT_H * LPR;           // 7,864,320 (multiple of 256)
    int block = 256;
    int grid = (n_thr + block - 1) / block;        // 30,720
    pad2d_edge_kernel<<<grid, block, 0, stream>>>(x, out, n_thr);
}